// Round 9
// baseline (1208.813 us; speedup 1.0000x reference)
//
#include <hip/hip_runtime.h>

#define K_DIM 256
__device__ __forceinline__ float lrelu_f(float x) { return x >= 0.f ? x : 0.2f * x; }

// ---------------- graph prep kernels ----------------

__global__ __launch_bounds__(256) void hist_kernel(const int* __restrict__ dst,
                                                   int* __restrict__ cnt, int E) {
  int e = blockIdx.x * 256 + threadIdx.x;
  if (e < E) atomicAdd(&cnt[dst[e]], 1);
}

__global__ __launch_bounds__(256) void dinv_kernel(const int* __restrict__ cnt,
                                                   float* __restrict__ dinv, int n) {
  int i = blockIdx.x * 256 + threadIdx.x;
  if (i < n) dinv[i] = rsqrtf((float)cnt[i] + 1.0f);
}

__global__ __launch_bounds__(256) void scan1_kernel(const int* __restrict__ cnt,
                                                    int* __restrict__ incl,
                                                    int* __restrict__ bsum, int n) {
  __shared__ int sm[256];
  int t = threadIdx.x;
  int i = blockIdx.x * 256 + t;
  int v = (i < n) ? cnt[i] : 0;
  sm[t] = v;
  __syncthreads();
  for (int off = 1; off < 256; off <<= 1) {
    int u = (t >= off) ? sm[t - off] : 0;
    __syncthreads();
    sm[t] += u;
    __syncthreads();
  }
  if (i < n) incl[i] = sm[t];
  if (t == 255) bsum[blockIdx.x] = sm[255];
}

__global__ __launch_bounds__(256) void scan2_kernel(const int* __restrict__ bsum,
                                                    int* __restrict__ boff, int nb) {
  __shared__ int sm[256];
  int t = threadIdx.x;
  int v = (t < nb) ? bsum[t] : 0;
  sm[t] = v;
  __syncthreads();
  for (int off = 1; off < 256; off <<= 1) {
    int u = (t >= off) ? sm[t - off] : 0;
    __syncthreads();
    sm[t] += u;
    __syncthreads();
  }
  boff[t] = sm[t] - v;  // exclusive
}

__global__ __launch_bounds__(256) void scan3_kernel(const int* __restrict__ incl,
                                                    const int* __restrict__ boff,
                                                    int* __restrict__ rowptr, int n) {
  int i = blockIdx.x * 256 + threadIdx.x;
  if (i < n) rowptr[i + 1] = incl[i] + boff[blockIdx.x];
  if (i == 0) rowptr[0] = 0;
}

__global__ __launch_bounds__(256) void scatter_kernel(const int* __restrict__ src,
                                                      const int* __restrict__ dst,
                                                      const int* __restrict__ rowptr,
                                                      int* __restrict__ cursor,
                                                      const float* __restrict__ dinv,
                                                      int* __restrict__ esrc,
                                                      float* __restrict__ ew, int E) {
  int e = blockIdx.x * 256 + threadIdx.x;
  if (e < E) {
    int d = dst[e];
    int p = rowptr[d] + atomicAdd(&cursor[d], 1);
    int s = src[e];
    esrc[p] = s;
    ew[p] = dinv[s];
  }
}

// ---------------- GEMM v2: 128x128 tile, 128 threads, 16x8 microtile ----------------
// R9: R8 analysis showed LDS-read-pipe-bound (4 b128 per 64 FMA -> 56% VALU
// ceiling, measured 51%). 16x8 microtile = 128 FMA per 6 b128 -> ~76% ceiling.
// 128 threads = 16 tx (8 cols each) x 8 ty (16 rows each as 4 quads of 4).
// Register staging (load->bar->write->bar->FMA) lets compiler hoist next
// step's global loads over FMA for free pipelining. VGPR ~200 is fine: grid
// 782 x 2 waves = 6.1 waves/CU is the binding limit, not VGPR (R6 lesson
// doesn't apply at 2-wave blocks).

template <bool LRELU, int NCOLS>
__global__ __launch_bounds__(128) void gemm16x8_kernel(const float* __restrict__ A,
                                                       const float* __restrict__ W,
                                                       float* __restrict__ H, int M) {
  constexpr int BK = 32;
  constexpr int PAD = 132;
  __shared__ float As[BK][PAD];
  __shared__ float Ws[BK][PAD];
  const int bm = blockIdx.x * 128;
  const int bn = blockIdx.y * 128;
  const int tid = threadIdx.x;   // 0..127
  const int tx = tid & 15;       // col group: cols tx*4+64h
  const int ty = tid >> 4;       // row group: rows 32q + ty*4 + i

  int ra = bm + tid;
  if (ra >= M) ra = M - 1;
  const float* Arow = A + (size_t)ra * K_DIM;
  const float* Wrow = W + (size_t)(bn + tid) * K_DIM;

  float acc[4][2][4][4];
#pragma unroll
  for (int q = 0; q < 4; q++)
#pragma unroll
    for (int h = 0; h < 2; h++)
#pragma unroll
      for (int i = 0; i < 4; i++)
#pragma unroll
        for (int j = 0; j < 4; j++) acc[q][h][i][j] = 0.f;

  for (int k0 = 0; k0 < K_DIM; k0 += BK) {
    float4 av[8], wv[8];
#pragma unroll
    for (int j = 0; j < 8; ++j) av[j] = *(const float4*)(Arow + k0 + 4 * j);
#pragma unroll
    for (int j = 0; j < 8; ++j) wv[j] = *(const float4*)(Wrow + k0 + 4 * j);
    if (LRELU) {
#pragma unroll
      for (int j = 0; j < 8; ++j) {
        av[j].x = lrelu_f(av[j].x); av[j].y = lrelu_f(av[j].y);
        av[j].z = lrelu_f(av[j].z); av[j].w = lrelu_f(av[j].w);
      }
    }
    __syncthreads();  // previous iteration's reads complete
#pragma unroll
    for (int j = 0; j < 8; ++j) {
      As[4 * j + 0][tid] = av[j].x;
      As[4 * j + 1][tid] = av[j].y;
      As[4 * j + 2][tid] = av[j].z;
      As[4 * j + 3][tid] = av[j].w;
      Ws[4 * j + 0][tid] = wv[j].x;
      Ws[4 * j + 1][tid] = wv[j].y;
      Ws[4 * j + 2][tid] = wv[j].z;
      Ws[4 * j + 3][tid] = wv[j].w;
    }
    __syncthreads();
#pragma unroll 8
    for (int kk = 0; kk < BK; ++kk) {
      float4 va[4];
      float4 vb[2];
#pragma unroll
      for (int q = 0; q < 4; ++q) va[q] = *(const float4*)&As[kk][32 * q + ty * 4];
#pragma unroll
      for (int h = 0; h < 2; ++h) vb[h] = *(const float4*)&Ws[kk][64 * h + tx * 4];
      float a[4][4] = {{va[0].x, va[0].y, va[0].z, va[0].w},
                       {va[1].x, va[1].y, va[1].z, va[1].w},
                       {va[2].x, va[2].y, va[2].z, va[2].w},
                       {va[3].x, va[3].y, va[3].z, va[3].w}};
      float b[2][4] = {{vb[0].x, vb[0].y, vb[0].z, vb[0].w},
                       {vb[1].x, vb[1].y, vb[1].z, vb[1].w}};
#pragma unroll
      for (int q = 0; q < 4; ++q)
#pragma unroll
        for (int h = 0; h < 2; ++h)
#pragma unroll
          for (int i = 0; i < 4; ++i)
#pragma unroll
            for (int j = 0; j < 4; ++j)
              acc[q][h][i][j] = fmaf(a[q][i], b[h][j], acc[q][h][i][j]);
    }
  }

#pragma unroll
  for (int q = 0; q < 4; ++q)
#pragma unroll
    for (int i = 0; i < 4; ++i) {
      int row = bm + 32 * q + ty * 4 + i;
      if (row < M) {
#pragma unroll
        for (int h = 0; h < 2; ++h) {
          float4 o;
          o.x = acc[q][h][i][0];
          o.y = acc[q][h][i][1];
          o.z = acc[q][h][i][2];
          o.w = acc[q][h][i][3];
          *(float4*)(H + (size_t)row * NCOLS + bn + 64 * h + tx * 4) = o;
        }
      }
    }
}

// ---------------- GEMM (R8 256-thread version, kept for NCOLS=128 last layer) ----------------

template <bool LRELU, int NCOLS>
__global__ __launch_bounds__(256) void gemm_kernel(const float* __restrict__ A,
                                                   const float* __restrict__ W,
                                                   float* __restrict__ H, int M) {
  constexpr int BK = 32;
  constexpr int PAD = 132;
  __shared__ float As[BK][PAD];
  __shared__ float Ws[BK][PAD];
  const int bm = blockIdx.x * 128;
  const int bn = blockIdx.y * 128;
  const int tid = threadIdx.x;
  const int tx = tid & 15;
  const int ty = tid >> 4;
  const int lr = tid >> 2;
  const int lk = (tid & 3) << 2;

  float acc[2][2][4][4];
#pragma unroll
  for (int a = 0; a < 2; a++)
#pragma unroll
    for (int b = 0; b < 2; b++)
#pragma unroll
      for (int i = 0; i < 4; i++)
#pragma unroll
        for (int j = 0; j < 4; j++) acc[a][b][i][j] = 0.f;

  for (int k0 = 0; k0 < K_DIM; k0 += BK) {
#pragma unroll
    for (int kh = 0; kh < 2; ++kh) {
      const int ks = kh * 16 + lk;
#pragma unroll
      for (int h = 0; h < 2; ++h) {
        int row = bm + h * 64 + lr;
        int rc = row < M ? row : M - 1;
        float4 v = *(const float4*)(A + (size_t)rc * K_DIM + k0 + ks);
        if (LRELU) {
          v.x = lrelu_f(v.x); v.y = lrelu_f(v.y); v.z = lrelu_f(v.z); v.w = lrelu_f(v.w);
        }
        As[ks + 0][h * 64 + lr] = v.x;
        As[ks + 1][h * 64 + lr] = v.y;
        As[ks + 2][h * 64 + lr] = v.z;
        As[ks + 3][h * 64 + lr] = v.w;
      }
#pragma unroll
      for (int h = 0; h < 2; ++h) {
        int row = bn + h * 64 + lr;
        float4 v = *(const float4*)(W + (size_t)row * K_DIM + k0 + ks);
        Ws[ks + 0][h * 64 + lr] = v.x;
        Ws[ks + 1][h * 64 + lr] = v.y;
        Ws[ks + 2][h * 64 + lr] = v.z;
        Ws[ks + 3][h * 64 + lr] = v.w;
      }
    }
    __syncthreads();
#pragma unroll 8
    for (int kk = 0; kk < BK; ++kk) {
      float4 va0 = *(const float4*)&As[kk][ty * 4];
      float4 va1 = *(const float4*)&As[kk][64 + ty * 4];
      float4 vb0 = *(const float4*)&Ws[kk][tx * 4];
      float4 vb1 = *(const float4*)&Ws[kk][64 + tx * 4];
      float a0[4] = {va0.x, va0.y, va0.z, va0.w};
      float a1[4] = {va1.x, va1.y, va1.z, va1.w};
      float b0[4] = {vb0.x, vb0.y, vb0.z, vb0.w};
      float b1[4] = {vb1.x, vb1.y, vb1.z, vb1.w};
#pragma unroll
      for (int i = 0; i < 4; i++)
#pragma unroll
        for (int j = 0; j < 4; j++) {
          acc[0][0][i][j] = fmaf(a0[i], b0[j], acc[0][0][i][j]);
          acc[0][1][i][j] = fmaf(a0[i], b1[j], acc[0][1][i][j]);
          acc[1][0][i][j] = fmaf(a1[i], b0[j], acc[1][0][i][j]);
          acc[1][1][i][j] = fmaf(a1[i], b1[j], acc[1][1][i][j]);
        }
    }
    __syncthreads();
  }

#pragma unroll
  for (int mh = 0; mh < 2; ++mh)
#pragma unroll
    for (int i = 0; i < 4; i++) {
      int row = bm + mh * 64 + ty * 4 + i;
      if (row < M) {
#pragma unroll
        for (int nh = 0; nh < 2; ++nh) {
          float4 o;
          o.x = acc[mh][nh][i][0];
          o.y = acc[mh][nh][i][1];
          o.z = acc[mh][nh][i][2];
          o.w = acc[mh][nh][i][3];
          *(float4*)(H + (size_t)row * NCOLS + bn + nh * 64 + tx * 4) = o;
        }
      }
    }
}

// ---------------- column-sliced aggregation (R7: WORKS, 124->~88us) ----------------
// out[i] = dinv_i*(sum_e dinv_s*h_s) + dinv_i^2*h_i + b
// Col-group g = blockIdx.x & 7 rides round-robin workgroup->XCD dispatch:
// each XCD's L2 sees a 1/8 column slice of H (6.4 MB unique vs 51 MB).

template <int COLS>
__global__ __launch_bounds__(256) void aggregate_kernel(
    const float* __restrict__ H, const int* __restrict__ rowptr,
    const int* __restrict__ esrc, const float* __restrict__ ew,
    const float* __restrict__ dinv, const float* __restrict__ bias,
    float* __restrict__ out, int n) {
  constexpr int CW = COLS / 8;
  constexpr int TPN = CW / 4;
  constexpr int NPB = 256 / TPN;
  const int g = blockIdx.x & 7;
  const int nb = blockIdx.x >> 3;
  const int t = threadIdx.x;
  const int ln = t / TPN;
  const int ct = t % TPN;
  const int node = nb * NPB + ln;
  if (node >= n) return;
  const int c0 = g * CW + ct * 4;
  const float* __restrict__ Hc = H + c0;
  const float di = dinv[node];

  float4 hs = *(const float4*)(Hc + (size_t)node * COLS);
  float a0 = di * hs.x, a1 = di * hs.y, a2 = di * hs.z, a3 = di * hs.w;

  const int e1 = rowptr[node + 1];
  int e = rowptr[node];
  for (; e + 4 <= e1; e += 4) {
    int s0 = esrc[e + 0], s1 = esrc[e + 1], s2 = esrc[e + 2], s3 = esrc[e + 3];
    float w0 = ew[e + 0], w1 = ew[e + 1], w2 = ew[e + 2], w3 = ew[e + 3];
    float4 h0 = *(const float4*)(Hc + (size_t)s0 * COLS);
    float4 h1 = *(const float4*)(Hc + (size_t)s1 * COLS);
    float4 h2 = *(const float4*)(Hc + (size_t)s2 * COLS);
    float4 h3 = *(const float4*)(Hc + (size_t)s3 * COLS);
    a0 = fmaf(w3, h3.x, fmaf(w2, h2.x, fmaf(w1, h1.x, fmaf(w0, h0.x, a0))));
    a1 = fmaf(w3, h3.y, fmaf(w2, h2.y, fmaf(w1, h1.y, fmaf(w0, h0.y, a1))));
    a2 = fmaf(w3, h3.z, fmaf(w2, h2.z, fmaf(w1, h1.z, fmaf(w0, h0.z, a2))));
    a3 = fmaf(w3, h3.w, fmaf(w2, h2.w, fmaf(w1, h1.w, fmaf(w0, h0.w, a3))));
  }
  for (; e < e1; ++e) {
    int s = esrc[e];
    float w = ew[e];
    float4 h = *(const float4*)(Hc + (size_t)s * COLS);
    a0 = fmaf(w, h.x, a0);
    a1 = fmaf(w, h.y, a1);
    a2 = fmaf(w, h.z, a2);
    a3 = fmaf(w, h.w, a3);
  }

  float4 b = *(const float4*)(bias + c0);
  float4 o;
  o.x = fmaf(di, a0, b.x);
  o.y = fmaf(di, a1, b.y);
  o.z = fmaf(di, a2, b.z);
  o.w = fmaf(di, a3, b.w);
  *(float4*)(out + (size_t)node * COLS + c0) = o;
}

// ---------------- launch ----------------

extern "C" void kernel_launch(void* const* d_in, const int* in_sizes, int n_in,
                              void* d_out, int out_size, void* d_ws, size_t ws_size,
                              hipStream_t stream) {
  (void)n_in; (void)out_size; (void)ws_size;
  const float* x = (const float*)d_in[0];
  const int N = in_sizes[0] / 256;
  const int* ei = (const int*)d_in[1];
  const int E = in_sizes[1] / 2;
  const int* srcp = ei;
  const int* dstp = ei + E;
  const float* Wl[6];
  const float* Bl[6];
  for (int i = 0; i < 6; i++) {
    Wl[i] = (const float*)d_in[2 + 2 * i];
    Bl[i] = (const float*)d_in[3 + 2 * i];
  }
  float* out = (float*)d_out;

  char* p = (char*)d_ws;
  auto carve = [&](size_t bytes) {
    char* r = p;
    p += (bytes + 255) & ~(size_t)255;
    return (void*)r;
  };
  float* bufA = (float*)carve((size_t)N * 256 * 4);
  float* bufB = (float*)carve((size_t)N * 256 * 4);
  int* cnt = (int*)carve((size_t)N * 4);
  float* dinv = (float*)carve((size_t)N * 4);
  int* incl = (int*)carve((size_t)N * 4);
  int* rowptr = (int*)carve((size_t)(N + 1) * 4);
  int* esrc = (int*)carve((size_t)E * 4);
  float* ew = (float*)carve((size_t)E * 4);
  int* bsum = (int*)carve(1024);
  int* boff = (int*)carve(1024);

  const int NB = (N + 255) / 256;

  hipMemsetAsync(cnt, 0, (size_t)N * 4, stream);
  hist_kernel<<<(E + 255) / 256, 256, 0, stream>>>(dstp, cnt, E);
  dinv_kernel<<<NB, 256, 0, stream>>>(cnt, dinv, N);
  scan1_kernel<<<NB, 256, 0, stream>>>(cnt, incl, bsum, N);
  scan2_kernel<<<1, 256, 0, stream>>>(bsum, boff, NB);
  scan3_kernel<<<NB, 256, 0, stream>>>(incl, boff, rowptr, N);
  hipMemsetAsync(cnt, 0, (size_t)N * 4, stream);
  scatter_kernel<<<(E + 255) / 256, 256, 0, stream>>>(srcp, dstp, rowptr, cnt, dinv,
                                                      esrc, ew, E);

  const int gm = (N + 127) / 128;
  const int gagg256 = 8 * ((N + 31) / 32);
  const int gagg128 = 8 * ((N + 63) / 64);

  // layer 1 (no lrelu on input)
  gemm16x8_kernel<false, 256><<<dim3(gm, 2), 128, 0, stream>>>(x, Wl[0], bufB, N);
  aggregate_kernel<256><<<gagg256, 256, 0, stream>>>(bufB, rowptr, esrc, ew, dinv, Bl[0], bufA, N);
  // layers 2..5
  for (int l = 1; l < 5; ++l) {
    gemm16x8_kernel<true, 256><<<dim3(gm, 2), 128, 0, stream>>>(bufA, Wl[l], bufB, N);
    aggregate_kernel<256><<<gagg256, 256, 0, stream>>>(bufB, rowptr, esrc, ew, dinv, Bl[l], bufA, N);
  }
  // layer 6 (out dim 128) -> d_out (256-thread kernel: better occupancy at this grid)
  gemm_kernel<true, 128><<<dim3(gm, 1), 256, 0, stream>>>(bufA, Wl[5], bufB, N);
  aggregate_kernel<128><<<gagg128, 256, 0, stream>>>(bufB, rowptr, esrc, ew, dinv, Bl[5], out, N);
}